// Round 19
// baseline (360.604 us; speedup 1.0000x reference)
//
#include <hip/hip_runtime.h>

#define NN     256
#define NF     127
#define DIM    128
#define NH     8
#define DH     64
#define INNER  512
#define DEPTH  6
#define NB     512
#define ATTN_SCALE 0.125f
#define LN_EPS 1e-5f

typedef _Float16 f16;
union H8 { uint4 u; f16 h[8]; };

#define FMA4(A_, S_, V_) { A_.x=fmaf(S_,(V_).x,A_.x); A_.y=fmaf(S_,(V_).y,A_.y); \
                           A_.z=fmaf(S_,(V_).z,A_.z); A_.w=fmaf(S_,(V_).w,A_.w); }

__device__ __forceinline__ float wred_sum(float v){
#pragma unroll
  for(int o=32;o;o>>=1) v += __shfl_xor(v,o);
  return v;
}
__device__ __forceinline__ float wred_max(float v){
#pragma unroll
  for(int o=32;o;o>>=1) v = fmaxf(v,__shfl_xor(v,o));
  return v;
}
__device__ __forceinline__ float2 wred_sum2(float a, float b){
#pragma unroll
  for(int o=32;o;o>>=1){ a += __shfl_xor(a,o); b += __shfl_xor(b,o); }
  return make_float2(a,b);
}

// In-wave LayerNorm of a 128-dim row held as (n0,n1) = dims (l, l+64) per lane.
__device__ __forceinline__ void ln_wave(float n0, float n1,
                                        const float* g, const float* b, int l,
                                        float& x0, float& x1){
  float2 sv = wred_sum2(n0+n1, n0*n0+n1*n1);
  float m  = sv.x*(1.f/DIM);
  float var = sv.y*(1.f/DIM) - m*m;
  float rs = rsqrtf(var + LN_EPS);
  x0 = (n0-m)*rs*g[l]    + b[l];
  x1 = (n1-m)*rs*g[64+l] + b[64+l];
}

// In-wave gated residual. No barriers.
__device__ __forceinline__ void gate_wave(float o0, float o1, float& n0, float& n1,
                                          const float* Wg, int l){
  float gv = o0*Wg[l]    + n0*Wg[DIM+l]    + (o0-n0)*Wg[2*DIM+l]
           + o1*Wg[64+l] + n1*Wg[DIM+64+l] + (o1-n1)*Wg[2*DIM+64+l];
  gv = wred_sum(gv);
  float gate = 1.f/(1.f + expf(-gv));
  n0 = o0*gate + n0*(1.f-gate);
  n1 = o1*gate + n1*(1.f-gate);
}

// ---- fp16-weight matvec partials ----
// x[128] @ W[128][512]h -> SC[fg*512+c], fg in [0,8)
__device__ __forceinline__ void mvp128_512h(const float* __restrict__ xin,
                                            const f16* __restrict__ W,
                                            float* __restrict__ SC, int t){
  const int cg8 = (t&63)<<3, fg = t>>6, f0 = fg<<4;
  const f16* __restrict__ p = W + f0*INNER + cg8;
  float4 a0 = make_float4(0.f,0.f,0.f,0.f), a1 = a0;
#pragma unroll
  for(int k=0;k<16;k++){
    H8 wv; wv.u = *(const uint4*)(p + k*INNER);
    float x = xin[f0+k];
    a0.x=fmaf(x,(float)wv.h[0],a0.x); a0.y=fmaf(x,(float)wv.h[1],a0.y);
    a0.z=fmaf(x,(float)wv.h[2],a0.z); a0.w=fmaf(x,(float)wv.h[3],a0.w);
    a1.x=fmaf(x,(float)wv.h[4],a1.x); a1.y=fmaf(x,(float)wv.h[5],a1.y);
    a1.z=fmaf(x,(float)wv.h[6],a1.z); a1.w=fmaf(x,(float)wv.h[7],a1.w);
  }
  *(float4*)(SC + fg*INNER + cg8)     = a0;
  *(float4*)(SC + fg*INNER + cg8 + 4) = a1;
}
// a[512] @ W[512][128]h -> SC[fg*128+c], fg in [0,32)
__device__ __forceinline__ void mvp512_128h(const float* __restrict__ ain,
                                            const f16* __restrict__ W,
                                            float* __restrict__ SC, int t){
  const int cg8 = (t&15)<<3, fg = t>>4, f0 = fg<<4;
  const f16* __restrict__ p = W + f0*DIM + cg8;
  float4 a0 = make_float4(0.f,0.f,0.f,0.f), a1 = a0;
#pragma unroll
  for(int k=0;k<16;k++){
    H8 wv; wv.u = *(const uint4*)(p + k*DIM);
    float x = ain[f0+k];
    a0.x=fmaf(x,(float)wv.h[0],a0.x); a0.y=fmaf(x,(float)wv.h[1],a0.y);
    a0.z=fmaf(x,(float)wv.h[2],a0.z); a0.w=fmaf(x,(float)wv.h[3],a0.w);
    a1.x=fmaf(x,(float)wv.h[4],a1.x); a1.y=fmaf(x,(float)wv.h[5],a1.y);
    a1.z=fmaf(x,(float)wv.h[6],a1.z); a1.w=fmaf(x,(float)wv.h[7],a1.w);
  }
  *(float4*)(SC + fg*DIM + cg8)     = a0;
  *(float4*)(SC + fg*DIM + cg8 + 4) = a1;
}

// ---- fused init kernel, grid 800:
//   blocks 0..255   : node-init + LN1 -> nodes, xg0 (no QKV)
//   blocks 256..287 : layer-invariant edge planes -> ebg
//   blocks 288..799 : fp32->fp16 conversion of Wo, W1, W2
__global__ __launch_bounds__(512) void k_init(const float* atom_emb, const float* noise,
    float* nodes, const float* ln1_g, const float* ln1_b, float* xg0,
    const int* bonds, const float* coords, float* ebg,
    const float* Wo, const float* W1, const float* W2,
    f16* Woh, f16* W1h, f16* W2h){
  __shared__ __align__(16) float ebs[8*768];
  const int t = threadIdx.x, bid = blockIdx.x;
  if(bid >= 288){
    const int NQ = DEPTH*DIM*INNER;
    for(int k = (bid-288)*512 + t; k < 3*NQ; k += 512*512){
      if(k < NQ)        W1h[k]      = (f16)W1[k];
      else if(k < 2*NQ) Woh[k-NQ]   = (f16)Wo[k-NQ];
      else              W2h[k-2*NQ] = (f16)W2[k-2*NQ];
    }
    return;
  }
  if(bid >= NN){
    const int i0 = (bid-NN)<<3;
#pragma unroll
    for(int cc=0; cc<12; cc++) ebs[cc*512 + t] = 0.f;
    __syncthreads();
    {
      const int bi = bonds[2*t], bj = bonds[2*t+1];
      const bool hi = (bi>=i0 && bi<i0+8), hj = (bj>=i0 && bj<i0+8);
      if(hi || hj){
        float dx = coords[3*bi+0] - coords[3*bj+0];
        float dy = coords[3*bi+1] - coords[3*bj+1];
        float dz = coords[3*bi+2] - coords[3*bj+2];
        if(hi){ float* e = ebs + (bi-i0)*768; e[bj]=dx;  e[256+bj]=dy;  e[512+bj]=dz;  }
        if(hj){ float* e = ebs + (bj-i0)*768; e[bi]=-dx; e[256+bi]=-dy; e[512+bi]=-dz; }
      }
    }
    __syncthreads();
#pragma unroll
    for(int cc=0; cc<12; cc++) ebg[(size_t)i0*768 + cc*512 + t] = ebs[cc*512 + t];
    return;
  }
  const int i = bid, w = t>>6, l = t&63;
  float nd0 = (l<NF)?    atom_emb[i*NF + l]      : noise[0];
  float nd1 = (64+l<NF)? atom_emb[i*NF + 64 + l] : noise[0];
  float x0, x1;
  ln_wave(nd0, nd1, ln1_g, ln1_b, l, x0, x1);
  if(w==0){
    nodes[i*DIM + l] = nd0; nodes[i*DIM + 64 + l] = nd1;
    xg0[i*DIM + l] = x0;    xg0[i*DIM + 64 + l] = x1;
  }
}

// ---- QKV GEMM: X[256x128] @ [Wq | Wkv] -> q, kT, v  (fp32) ----
// grid 192 = 32 row-tiles(8 rows) x 6 col-tiles(256 cols of 1536).
// lane->col (full 1KB/wave coalescing); wave->row (LDS broadcast X reads);
// dual f-half pointer streams for MLP.
__global__ __launch_bounds__(512) void k_qkv(
    const float* __restrict__ xg,
    const float* __restrict__ Wq, const float* __restrict__ bq,
    const float* __restrict__ Wkv, const float* __restrict__ bkv,
    const float* __restrict__ be,
    float* __restrict__ qg, float* __restrict__ kT, float* __restrict__ vg){
  __shared__ __align__(16) float xs[8*DIM];   // 4KB row-tile of X
  const int t = threadIdx.x, bid = blockIdx.x;
  const int rt = bid / 6, ct = bid % 6;
  const int cb = ct*256;
  const int slot = t>>6;                 // wave = row slot
  const int c4 = (t&63)<<2;              // lane's col offset in tile
  const int c = cb + c4;                 // absolute col in [0,1536)
  const int r = rt*8 + slot;             // output row
  if(t < 256)
    *(float4*)(xs + (t<<2)) = *(const float4*)(xg + (size_t)rt*8*DIM + (t<<2));
  __syncthreads();
  const float* __restrict__ xr = xs + slot*DIM;   // wave-uniform -> LDS broadcast
  float4 a0 = make_float4(0.f,0.f,0.f,0.f), a1 = a0;
  if(cb < 512){
    // ---- q region ----
    const float* __restrict__ p0 = Wq + c;
    const float* __restrict__ p1 = Wq + 64*INNER + c;
#pragma unroll 16
    for(int f=0; f<64; f++){
      float4 w0 = *(const float4*)(p0); p0 += INNER;
      float4 w1 = *(const float4*)(p1); p1 += INNER;
      float x0 = xr[f], x1 = xr[64+f];
      FMA4(a0, x0, w0); FMA4(a1, x1, w1);
    }
    float4 bb = *(const float4*)(bq + c);
    a0.x += a1.x + bb.x; a0.y += a1.y + bb.y;
    a0.z += a1.z + bb.z; a0.w += a1.w + bb.w;
    *(float4*)(qg + r*INNER + c) = a0;
  } else {
    // ---- kv region ----
    const int wc = c - 512;                     // Wkv column in [0,1024)
    const float* __restrict__ p0 = Wkv + wc;
    const float* __restrict__ p1 = Wkv + 64*(2*INNER) + wc;
#pragma unroll 16
    for(int f=0; f<64; f++){
      float4 w0 = *(const float4*)(p0); p0 += 2*INNER;
      float4 w1 = *(const float4*)(p1); p1 += 2*INNER;
      float x0 = xr[f], x1 = xr[64+f];
      FMA4(a0, x0, w0); FMA4(a1, x1, w1);
    }
    if(wc < 512){                               // k: transposed store
      kT[(wc+0)*NN + r] = a0.x + a1.x + bkv[wc+0] + be[wc+0];
      kT[(wc+1)*NN + r] = a0.y + a1.y + bkv[wc+1] + be[wc+1];
      kT[(wc+2)*NN + r] = a0.z + a1.z + bkv[wc+2] + be[wc+2];
      kT[(wc+3)*NN + r] = a0.w + a1.w + bkv[wc+3] + be[wc+3];
    } else {                                    // v
      const int vc = wc - 512;
      a0.x += a1.x + bkv[512+vc+0] + be[vc+0];
      a0.y += a1.y + bkv[512+vc+1] + be[vc+1];
      a0.z += a1.z + bkv[512+vc+2] + be[vc+2];
      a0.w += a1.w + bkv[512+vc+3] + be[vc+3];
      *(float4*)(vg + r*INNER + vc) = a0;
    }
  }
}

// ---- attention: block = (head h, 8-row tile); wave w = row i0+w (R14-proven) ----
__global__ __launch_bounds__(512) void k_attn(
    const float* __restrict__ qg, const float* __restrict__ kT,
    const float* __restrict__ vg, const float* __restrict__ ebg,
    const float* __restrict__ We, float* __restrict__ aog,
    const f16* __restrict__ pfA, const f16* __restrict__ pfB,
    const f16* __restrict__ pfC)
{
  __shared__ __align__(16) float kTs[64*NN];    // 64 KB: [o][j]
  __shared__ __align__(16) float vs[NN*64];     // 64 KB: [j][c]
  __shared__ __align__(16) float aW[8][NN];     // 8 KB
  __shared__ __align__(16) float qsm[8*DH];     // 2 KB
  const int t = threadIdx.x;
  const int h = blockIdx.x >> 5, i0 = (blockIdx.x & 31) << 3;
  const int w = t>>6, l = t&63;
  const int qb = h*DH, j0 = l<<2;

  {
    const float* kbase = kT + qb*NN;
#pragma unroll
    for(int r=0;r<8;r++){
      int idx = r*2048 + (t<<2);
      *(float4*)(kTs + idx) = *(const float4*)(kbase + idx);
    }
    const int jr = t>>4, c4 = (t&15)<<2;
#pragma unroll
    for(int p=0;p<8;p++){
      int j = p*32 + jr;
      *(float4*)(vs + j*64 + c4) = *(const float4*)(vg + j*INNER + qb + c4);
    }
  }
  qsm[w*DH + l] = qg[(i0+w)*INNER + qb + l];

  // L2 warm of this layer's k_layer weight streams (XCD-sliced)
  {
    const int s = blockIdx.x >> 3;
    unsigned keep = 0u;
    if(t < 256){
      keep ^= ((const uint4*)((const char*)pfA + (size_t)s*4096))[t].x;  // Wo_l
      keep ^= ((const uint4*)((const char*)pfB + (size_t)s*4096))[t].y;  // W1_l
      keep ^= ((const uint4*)((const char*)pfC + (size_t)s*4096))[t].z;  // W2_l
    }
    asm volatile("" :: "v"(keep));
  }
  __syncthreads();

  float qwe0, qwe1, qwe2;
  {
    float qv = qsm[w*DH + l];
    qwe0 = qv*We[0*INNER + qb + l];
    qwe1 = qv*We[1*INNER + qb + l];
    qwe2 = qv*We[2*INNER + qb + l];
#pragma unroll
    for(int o=32;o;o>>=1){
      qwe0 += __shfl_xor(qwe0,o); qwe1 += __shfl_xor(qwe1,o); qwe2 += __shfl_xor(qwe2,o);
    }
  }
  float s0=0.f,s1=0.f,s2=0.f,s3=0.f;
#pragma unroll 8
  for(int o=0;o<DH;o++){
    float qv = qsm[w*DH + o];
    float4 kk = *(const float4*)(kTs + o*NN + j0);
    s0=fmaf(qv,kk.x,s0); s1=fmaf(qv,kk.y,s1); s2=fmaf(qv,kk.z,s2); s3=fmaf(qv,kk.w,s3);
  }
  const float* __restrict__ e = ebg + (size_t)(i0+w)*768;
  float4 ex = *(const float4*)(e + j0);
  float4 ey = *(const float4*)(e + 256 + j0);
  float4 ez = *(const float4*)(e + 512 + j0);
  s0 = (s0 + qwe0*ex.x + qwe1*ey.x + qwe2*ez.x)*ATTN_SCALE;
  s1 = (s1 + qwe0*ex.y + qwe1*ey.y + qwe2*ez.y)*ATTN_SCALE;
  s2 = (s2 + qwe0*ex.z + qwe1*ey.z + qwe2*ez.z)*ATTN_SCALE;
  s3 = (s3 + qwe0*ex.w + qwe1*ey.w + qwe2*ez.w)*ATTN_SCALE;
  float mx = wred_max(fmaxf(fmaxf(s0,s1),fmaxf(s2,s3)));
  float p0=expf(s0-mx), p1=expf(s1-mx), p2=expf(s2-mx), p3=expf(s3-mx);
  float inv = 1.f / wred_sum(p0+p1+p2+p3);
  float a0=p0*inv, a1=p1*inv, a2=p2*inv, a3=p3*inv;
  *(float4*)(aW[w] + j0) = make_float4(a0,a1,a2,a3);
  float c0 = a0*ex.x + a1*ex.y + a2*ex.z + a3*ex.w;
  float c1 = a0*ey.x + a1*ey.y + a2*ey.z + a3*ey.w;
  float c2 = a0*ez.x + a1*ez.y + a2*ez.z + a3*ez.w;
  c0 = wred_sum(c0); c1 = wred_sum(c1); c2 = wred_sum(c2);
  __builtin_amdgcn_wave_barrier();   // order aW writes before same-wave aW reads
  const float* aww = aW[w];
  float acc0 = 0.f, acc1 = 0.f;
#pragma unroll 8
  for(int j=0;j<NN;j+=2){
    acc0 = fmaf(aww[j],   vs[j*64 + l],     acc0);
    acc1 = fmaf(aww[j+1], vs[(j+1)*64 + l], acc1);
  }
  float ov = acc0 + acc1
           + c0*We[0*INNER + qb + l]
           + c1*We[1*INNER + qb + l]
           + c2*We[2*INNER + qb + l];
  aog[(i0+w)*INNER + qb + l] = ov;
}

// ---- per-row layer tail: Wo+gate1+LN2+FFN+gate2 -> nodes, xg' (or energy) ----
__global__ __launch_bounds__(512) void k_layer(
    float* nodes, const float* __restrict__ aog, float* xg_n,
    const f16* __restrict__ Woh, const float* __restrict__ bo,
    const float* __restrict__ Wg1,
    const float* __restrict__ ln2_g, const float* __restrict__ ln2_b,
    const f16* __restrict__ W1h, const float* __restrict__ b1,
    const f16* __restrict__ W2h, const float* __restrict__ b2,
    const float* __restrict__ Wg2,
    const float* __restrict__ ln1_g_n, const float* __restrict__ ln1_b_n,
    const float* __restrict__ out_w, const float* __restrict__ out_b,
    float* eout, int has_next)
{
  __shared__ __align__(16) float SC[4096];   // matvec partials
  __shared__ __align__(16) float qs[INNER];  // FFN hidden
  __shared__ __align__(16) float aos[INNER]; // attention output row
  __shared__ __align__(16) float xsm[DIM];
  const int t = threadIdx.x, i = blockIdx.x;
  const int w = t>>6, l = t&63;

  aos[t] = aog[i*INNER + t];
  float nd0 = nodes[i*DIM + l];        // per-wave redundant row state
  float nd1 = nodes[i*DIM + 64 + l];
  __syncthreads();                               // B1

  // ---- Wo (fp16) + gate1 + LN2 ----
  mvp512_128h(aos, Woh, SC, t);
  __syncthreads();                               // B2
  {
    float o0 = bo[l], o1 = bo[64+l];
#pragma unroll
    for(int fg=0; fg<32; fg++){ o0 += SC[fg*DIM + l]; o1 += SC[fg*DIM + 64 + l]; }
    gate_wave(o0, o1, nd0, nd1, Wg1, l);
    float x0, x1;
    ln_wave(nd0, nd1, ln2_g, ln2_b, l, x0, x1);
    xsm[l] = x0; xsm[64+l] = x1;   // each wave writes the full row (own-wave reads)
  }
  __syncthreads();                               // B3 (xsm ready; SC free)

  // ---- FFN (fp16) ----
  mvp128_512h(xsm, W1h, SC, t);
  __syncthreads();                               // B4
  {
    float a = b1[t];
#pragma unroll
    for(int fg=0; fg<8; fg++) a += SC[fg*INNER + t];
    qs[t] = 0.5f*a*(1.f + erff(a*0.70710678118654752440f));
  }
  __syncthreads();                               // B5 (hidden ready; SC free)
  mvp512_128h(qs, W2h, SC, t);
  __syncthreads();                               // B6
  {
    float y0 = b2[l], y1 = b2[64+l];
#pragma unroll
    for(int fg=0; fg<32; fg++){ y0 += SC[fg*DIM + l]; y1 += SC[fg*DIM + 64 + l]; }
    gate_wave(y0, y1, nd0, nd1, Wg2, l);
    if(w==0){ nodes[i*DIM + l] = nd0; nodes[i*DIM + 64 + l] = nd1; }
    if(has_next){
      float x0, x1;
      ln_wave(nd0, nd1, ln1_g_n, ln1_b_n, l, x0, x1);
      if(w==0){ xg_n[i*DIM + l] = x0; xg_n[i*DIM + 64 + l] = x1; }
    } else if(w==0){
      float ev = nd0*out_w[l] + nd1*out_w[64+l];
      ev = wred_sum(ev);
      if(l==0) eout[i] = ev + out_b[0];
    }
  }
}

extern "C" void kernel_launch(void* const* d_in, const int* in_sizes, int n_in,
                              void* d_out, int out_size, void* d_ws, size_t ws_size,
                              hipStream_t stream){
  const float* coords   = (const float*)d_in[0];
  const int*   bonds    = (const int*  )d_in[1];
  const float* noise    = (const float*)d_in[2];
  const float* atom_emb = (const float*)d_in[3];
  const float* ln1_g = (const float*)d_in[4];
  const float* ln1_b = (const float*)d_in[5];
  const float* Wq    = (const float*)d_in[6];
  const float* bq    = (const float*)d_in[7];
  const float* Wkv   = (const float*)d_in[8];
  const float* bkv   = (const float*)d_in[9];
  const float* We    = (const float*)d_in[10];
  const float* be    = (const float*)d_in[11];
  const float* Wo    = (const float*)d_in[12];
  const float* bo    = (const float*)d_in[13];
  const float* Wg1   = (const float*)d_in[14];
  const float* ln2_g = (const float*)d_in[15];
  const float* ln2_b = (const float*)d_in[16];
  const float* W1    = (const float*)d_in[17];
  const float* b1    = (const float*)d_in[18];
  const float* W2    = (const float*)d_in[19];
  const float* b2    = (const float*)d_in[20];
  const float* Wg2   = (const float*)d_in[21];
  const float* out_w = (const float*)d_in[22];
  const float* out_b = (const float*)d_in[23];

  // workspace carve (bytes); total ~5.6 MB
  char* base = (char*)d_ws;
  float* nodes = (float*)(base);                    // 131072 B
  float* qb    = (float*)(base + 131072);           // 524288 B
  float* kb    = (float*)(base + 655360);           // 524288 B
  float* vb    = (float*)(base + 1179648);          // 524288 B
  float* aog   = (float*)(base + 1703936);          // 524288 B
  float* ebg   = (float*)(base + 2228224);          // 786432 B
  float* xg0   = (float*)(base + 3014656);          // 131072 B
  float* xg1   = (float*)(base + 3145728);          // 131072 B
  f16*   Woh   = (f16*  )(base + 3276800);          // 786432 B
  f16*   W1h   = (f16*  )(base + 4063232);
  f16*   W2h   = (f16*  )(base + 4849664);
  float* eout  = (float*)d_out;

  k_init<<<800, 512, 0, stream>>>(atom_emb, noise, nodes, ln1_g, ln1_b, xg0,
                                  bonds, coords, ebg,
                                  Wo, W1, W2, Woh, W1h, W2h);
  k_qkv<<<192, 512, 0, stream>>>(xg0, Wq, bq, Wkv, bkv, be, qb, kb, vb);
  for(int l=0; l<DEPTH; l++){
    int has_next = (l < DEPTH-1);
    int ln = has_next ? l+1 : l;    // keep pointers valid when unused
    float* xin_next = ((l+1)&1)? xg1 : xg0;
    const f16* Woh_l  = Woh + (size_t)l*INNER*DIM;
    const f16* W1h_l  = W1h + (size_t)l*DIM*4*DIM;
    const f16* W2h_l  = W2h + (size_t)l*4*DIM*DIM;
    k_attn<<<NN, 512, 0, stream>>>(
      qb, kb, vb, ebg,
      We + (size_t)l*3*INNER, aog,
      Woh_l, W1h_l, W2h_l);
    k_layer<<<NN, 512, 0, stream>>>(
      nodes, aog, xin_next,
      Woh_l, bo + (size_t)l*DIM, Wg1 + (size_t)l*3*DIM,
      ln2_g + (size_t)l*DIM, ln2_b + (size_t)l*DIM,
      W1h_l, b1 + (size_t)l*4*DIM,
      W2h_l, b2 + (size_t)l*DIM, Wg2 + (size_t)l*3*DIM,
      ln1_g + (size_t)ln*DIM, ln1_b + (size_t)ln*DIM,
      out_w, out_b, eout, has_next);
    if(has_next){
      k_qkv<<<192, 512, 0, stream>>>(xin_next,
        Wq  + (size_t)ln*DIM*INNER,   bq  + (size_t)ln*INNER,
        Wkv + (size_t)ln*DIM*2*INNER, bkv + (size_t)ln*2*INNER,
        be  + (size_t)ln*INNER,
        qb, kb, vb);
    }
  }
}

// Round 20
// 267.914 us; speedup vs baseline: 1.3460x; 1.3460x over previous
//
#include <hip/hip_runtime.h>

#define NN     256
#define NF     127
#define DIM    128
#define NH     8
#define DH     64
#define INNER  512
#define DEPTH  6
#define NB     512
#define ATTN_SCALE 0.125f
#define LN_EPS 1e-5f

typedef _Float16 f16;
union H8 { uint4 u; f16 h[8]; };

#define FMA4(A_, S_, V_) { A_.x=fmaf(S_,(V_).x,A_.x); A_.y=fmaf(S_,(V_).y,A_.y); \
                           A_.z=fmaf(S_,(V_).z,A_.z); A_.w=fmaf(S_,(V_).w,A_.w); }

__device__ __forceinline__ float wred_sum(float v){
#pragma unroll
  for(int o=32;o;o>>=1) v += __shfl_xor(v,o);
  return v;
}
__device__ __forceinline__ float wred_max(float v){
#pragma unroll
  for(int o=32;o;o>>=1) v = fmaxf(v,__shfl_xor(v,o));
  return v;
}
__device__ __forceinline__ float2 wred_sum2(float a, float b){
#pragma unroll
  for(int o=32;o;o>>=1){ a += __shfl_xor(a,o); b += __shfl_xor(b,o); }
  return make_float2(a,b);
}

// In-wave LayerNorm of a 128-dim row held as (n0,n1) = dims (l, l+64) per lane.
__device__ __forceinline__ void ln_wave(float n0, float n1,
                                        const float* g, const float* b, int l,
                                        float& x0, float& x1){
  float2 sv = wred_sum2(n0+n1, n0*n0+n1*n1);
  float m  = sv.x*(1.f/DIM);
  float var = sv.y*(1.f/DIM) - m*m;
  float rs = rsqrtf(var + LN_EPS);
  x0 = (n0-m)*rs*g[l]    + b[l];
  x1 = (n1-m)*rs*g[64+l] + b[64+l];
}

// In-wave gated residual. No barriers.
__device__ __forceinline__ void gate_wave(float o0, float o1, float& n0, float& n1,
                                          const float* Wg, int l){
  float gv = o0*Wg[l]    + n0*Wg[DIM+l]    + (o0-n0)*Wg[2*DIM+l]
           + o1*Wg[64+l] + n1*Wg[DIM+64+l] + (o1-n1)*Wg[2*DIM+64+l];
  gv = wred_sum(gv);
  float gate = 1.f/(1.f + expf(-gv));
  n0 = o0*gate + n0*(1.f-gate);
  n1 = o1*gate + n1*(1.f-gate);
}

// ---- fp16-weight matvec partials ----
// x[128] @ W[128][512]h -> SC[fg*512+c], fg in [0,8)
__device__ __forceinline__ void mvp128_512h(const float* __restrict__ xin,
                                            const f16* __restrict__ W,
                                            float* __restrict__ SC, int t){
  const int cg8 = (t&63)<<3, fg = t>>6, f0 = fg<<4;
  const f16* __restrict__ p = W + f0*INNER + cg8;
  float4 a0 = make_float4(0.f,0.f,0.f,0.f), a1 = a0;
#pragma unroll
  for(int k=0;k<16;k++){
    H8 wv; wv.u = *(const uint4*)(p + k*INNER);
    float x = xin[f0+k];
    a0.x=fmaf(x,(float)wv.h[0],a0.x); a0.y=fmaf(x,(float)wv.h[1],a0.y);
    a0.z=fmaf(x,(float)wv.h[2],a0.z); a0.w=fmaf(x,(float)wv.h[3],a0.w);
    a1.x=fmaf(x,(float)wv.h[4],a1.x); a1.y=fmaf(x,(float)wv.h[5],a1.y);
    a1.z=fmaf(x,(float)wv.h[6],a1.z); a1.w=fmaf(x,(float)wv.h[7],a1.w);
  }
  *(float4*)(SC + fg*INNER + cg8)     = a0;
  *(float4*)(SC + fg*INNER + cg8 + 4) = a1;
}
// a[512] @ W[512][128]h -> SC[fg*128+c], fg in [0,32)
__device__ __forceinline__ void mvp512_128h(const float* __restrict__ ain,
                                            const f16* __restrict__ W,
                                            float* __restrict__ SC, int t){
  const int cg8 = (t&15)<<3, fg = t>>4, f0 = fg<<4;
  const f16* __restrict__ p = W + f0*DIM + cg8;
  float4 a0 = make_float4(0.f,0.f,0.f,0.f), a1 = a0;
#pragma unroll
  for(int k=0;k<16;k++){
    H8 wv; wv.u = *(const uint4*)(p + k*DIM);
    float x = ain[f0+k];
    a0.x=fmaf(x,(float)wv.h[0],a0.x); a0.y=fmaf(x,(float)wv.h[1],a0.y);
    a0.z=fmaf(x,(float)wv.h[2],a0.z); a0.w=fmaf(x,(float)wv.h[3],a0.w);
    a1.x=fmaf(x,(float)wv.h[4],a1.x); a1.y=fmaf(x,(float)wv.h[5],a1.y);
    a1.z=fmaf(x,(float)wv.h[6],a1.z); a1.w=fmaf(x,(float)wv.h[7],a1.w);
  }
  *(float4*)(SC + fg*DIM + cg8)     = a0;
  *(float4*)(SC + fg*DIM + cg8 + 4) = a1;
}
// fp32: x[128] @ W[128][512] -> SC[fq*512+c], fq in [0,4)
__device__ __forceinline__ void mvp128_512f(const float* __restrict__ xin,
                                            const float* __restrict__ W,
                                            float* __restrict__ SC, int t){
  const int cg4 = (t&127)<<2, fq = t>>7;
  float4 acc = make_float4(0.f,0.f,0.f,0.f);
#pragma unroll 8
  for(int f=fq*32; f<fq*32+32; f++){
    float4 wv = *(const float4*)(W + f*INNER + cg4);
    float xv = xin[f];
    FMA4(acc, xv, wv);
  }
  *(float4*)(SC + fq*INNER + cg4) = acc;
}
// fp32: x[128] @ W[128][1024] -> SC[rh*1024+c], rh in [0,2)
__device__ __forceinline__ void mvp128_1024(const float* __restrict__ xin,
                                            const float* __restrict__ W,
                                            float* __restrict__ SC, int t){
  const int cg4 = (t&255)<<2, rh = t>>8;
  float4 acc = make_float4(0.f,0.f,0.f,0.f);
#pragma unroll 8
  for(int f=rh*64; f<rh*64+64; f++){
    float4 wv = *(const float4*)(W + f*(2*INNER) + cg4);
    float xv = xin[f];
    FMA4(acc, xv, wv);
  }
  *(float4*)(SC + rh*(2*INNER) + cg4) = acc;
}

// LN1 output xs[128] (LDS) -> q/k/v for row i. Wq fp16, Wkv fp32, K/V fp32 out.
// SC: 6144 floats. 1 barrier inside. (k_layer's next-layer tail)
__device__ __forceinline__ void qkv_tail(const float* __restrict__ xs, int i,
    const f16* __restrict__ Wqh, const float* __restrict__ bq,
    const float* __restrict__ Wkv, const float* __restrict__ bkv,
    const float* __restrict__ be, float* qgn, float* kTn, float* vgn,
    float* __restrict__ SC, int t){
  mvp128_512h(xs, Wqh, SC,        t);   // SC[0..4096)
  mvp128_1024(xs, Wkv, SC + 4096, t);   // SC[4096..6144)
  __syncthreads();
  {
    float s = bq[t];
#pragma unroll
    for(int fg=0; fg<8; fg++) s += SC[fg*INNER + t];
    qgn[i*INNER + t] = s;
  }
#pragma unroll
  for(int cc=0; cc<2; cc++){
    int c = t + cc*512;
    float sv = bkv[c] + SC[4096 + c] + SC[4096 + 1024 + c];
    if(c < INNER) kTn[c*NN + i]            = sv + be[c];
    else          vgn[i*INNER + c - INNER] = sv + be[c-INNER];
  }
}

// fp32-Wq variant for layer 0 (no dependency on fp16 conversion). SC: 4096 floats.
__device__ __forceinline__ void qkv_tail0f(const float* __restrict__ xs, int i,
    const float* __restrict__ Wq, const float* __restrict__ bq,
    const float* __restrict__ Wkv, const float* __restrict__ bkv,
    const float* __restrict__ be, float* qgn, float* kTn, float* vgn,
    float* __restrict__ SC, int t){
  mvp128_512f(xs, Wq,  SC,        t);   // SC[0..2048)
  mvp128_1024(xs, Wkv, SC + 2048, t);   // SC[2048..4096)
  __syncthreads();
  qgn[i*INNER + t] = bq[t] + SC[t] + SC[512+t] + SC[1024+t] + SC[1536+t];
#pragma unroll
  for(int cc=0; cc<2; cc++){
    int c = t + cc*512;
    float sv = bkv[c] + SC[2048 + c] + SC[2048 + 1024 + c];
    if(c < INNER) kTn[c*NN + i]            = sv + be[c];
    else          vgn[i*INNER + c - INNER] = sv + be[c-INNER];
  }
}

// ---- fused init kernel, grid 800:
//   blocks 0..255   : node-init + LN1 + layer-0 QKV (fp32 weights)
//   blocks 256..287 : layer-invariant edge planes -> ebg
//   blocks 288..799 : fp32->fp16 conversion of Wq, Wo, W1, W2
__global__ __launch_bounds__(512) void k_init(const float* atom_emb, const float* noise,
    float* nodes, const float* ln1_g, const float* ln1_b,
    const float* Wq, const float* bq, const float* Wkv, const float* bkv, const float* be,
    float* qg, float* kT, float* vg,
    const int* bonds, const float* coords, float* ebg,
    const float* Wo, const float* W1, const float* W2,
    f16* Wqh, f16* Woh, f16* W1h, f16* W2h){
  __shared__ __align__(16) float SC[4096];
  __shared__ __align__(16) float xsm[DIM];
  __shared__ __align__(16) float ebs[8*768];
  const int t = threadIdx.x, bid = blockIdx.x;
  if(bid >= 288){
    const int NQ = DEPTH*DIM*INNER;
    for(int k = (bid-288)*512 + t; k < 4*NQ; k += 512*512){
      float v; f16* dst;
      if(k < NQ)        { v = Wq[k];        dst = Wqh + k; }
      else if(k < 2*NQ) { v = Wo[k-NQ];     dst = Woh + (k-NQ); }
      else if(k < 3*NQ) { v = W1[k-2*NQ];   dst = W1h + (k-2*NQ); }
      else              { v = W2[k-3*NQ];   dst = W2h + (k-3*NQ); }
      *dst = (f16)v;
    }
    return;
  }
  if(bid >= NN){
    const int i0 = (bid-NN)<<3;
#pragma unroll
    for(int cc=0; cc<12; cc++) ebs[cc*512 + t] = 0.f;
    __syncthreads();
    {
      const int bi = bonds[2*t], bj = bonds[2*t+1];
      const bool hi = (bi>=i0 && bi<i0+8), hj = (bj>=i0 && bj<i0+8);
      if(hi || hj){
        float dx = coords[3*bi+0] - coords[3*bj+0];
        float dy = coords[3*bi+1] - coords[3*bj+1];
        float dz = coords[3*bi+2] - coords[3*bj+2];
        if(hi){ float* e = ebs + (bi-i0)*768; e[bj]=dx;  e[256+bj]=dy;  e[512+bj]=dz;  }
        if(hj){ float* e = ebs + (bj-i0)*768; e[bi]=-dx; e[256+bi]=-dy; e[512+bi]=-dz; }
      }
    }
    __syncthreads();
#pragma unroll
    for(int cc=0; cc<12; cc++) ebg[(size_t)i0*768 + cc*512 + t] = ebs[cc*512 + t];
    return;
  }
  const int i = bid, w = t>>6, l = t&63;
  float nd0 = (l<NF)?    atom_emb[i*NF + l]      : noise[0];
  float nd1 = (64+l<NF)? atom_emb[i*NF + 64 + l] : noise[0];
  if(w==0){ nodes[i*DIM + l] = nd0; nodes[i*DIM + 64 + l] = nd1; }
  float x0, x1;
  ln_wave(nd0, nd1, ln1_g, ln1_b, l, x0, x1);
  xsm[l] = x0; xsm[64+l] = x1;     // all waves write identical values (benign)
  __syncthreads();
  qkv_tail0f(xsm, i, Wq, bq, Wkv, bkv, be, qg, kT, vg, SC, t);
}

// ---- attention: block = (head h, 8-row tile); wave w = row i0+w; fp32 K/V ----
// K/V head-slices staged ONCE into LDS; PV lane-per-output-dim (R14-proven).
// Also L2-warms the upcoming k_layer's weight streams (XCD-sliced).
__global__ __launch_bounds__(512) void k_attn(
    const float* __restrict__ qg, const float* __restrict__ kT,
    const float* __restrict__ vg, const float* __restrict__ ebg,
    const float* __restrict__ We, float* __restrict__ aog,
    const f16* __restrict__ pfA, const f16* __restrict__ pfB,
    const f16* __restrict__ pfC, const f16* __restrict__ pfD,
    const float* __restrict__ pfE, int pf_next)
{
  __shared__ __align__(16) float kTs[64*NN];    // 64 KB: [o][j]
  __shared__ __align__(16) float vs[NN*64];     // 64 KB: [j][c]
  __shared__ __align__(16) float aW[8][NN];     // 8 KB
  __shared__ __align__(16) float qsm[8*DH];     // 2 KB
  const int t = threadIdx.x;
  const int h = blockIdx.x >> 5, i0 = (blockIdx.x & 31) << 3;
  const int w = t>>6, l = t&63;
  const int qb = h*DH, j0 = l<<2;

  {
    const float* kbase = kT + qb*NN;
#pragma unroll
    for(int r=0;r<8;r++){
      int idx = r*2048 + (t<<2);
      *(float4*)(kTs + idx) = *(const float4*)(kbase + idx);
    }
    const int jr = t>>4, c4 = (t&15)<<2;
#pragma unroll
    for(int p=0;p<8;p++){
      int j = p*32 + jr;
      *(float4*)(vs + j*64 + c4) = *(const float4*)(vg + j*INNER + qb + c4);
    }
  }
  qsm[w*DH + l] = qg[(i0+w)*INNER + qb + l];

  // L2 warm: blocks with bid&7==x share XCD x; slice s=bid>>3 (32 per XCD).
  {
    const int s = blockIdx.x >> 3;
    unsigned keep = 0u;
    if(t < 256){
      keep ^= ((const uint4*)((const char*)pfA + (size_t)s*4096))[t].x;  // Wo_l  (f16)
      keep ^= ((const uint4*)((const char*)pfB + (size_t)s*4096))[t].y;  // W1_l  (f16)
      keep ^= ((const uint4*)((const char*)pfC + (size_t)s*4096))[t].z;  // W2_l  (f16)
      if(pf_next)
        keep ^= ((const uint4*)((const char*)pfD + (size_t)s*4096))[t].w; // Wq'  (f16)
    }
    if(pf_next){
      keep ^= ((const uint4*)((const char*)pfE + (size_t)s*16384))[t].x;       // Wkv' lo
      keep ^= ((const uint4*)((const char*)pfE + (size_t)s*16384))[512 + t].x; // Wkv' hi
    }
    asm volatile("" :: "v"(keep));   // keep touches live (rule #17)
  }
  __syncthreads();

  float qwe0, qwe1, qwe2;
  {
    float qv = qsm[w*DH + l];
    qwe0 = qv*We[0*INNER + qb + l];
    qwe1 = qv*We[1*INNER + qb + l];
    qwe2 = qv*We[2*INNER + qb + l];
#pragma unroll
    for(int o=32;o;o>>=1){
      qwe0 += __shfl_xor(qwe0,o); qwe1 += __shfl_xor(qwe1,o); qwe2 += __shfl_xor(qwe2,o);
    }
  }
  // QK^T from LDS: lane l -> scores j0..j0+3 for row i0+w
  float s0=0.f,s1=0.f,s2=0.f,s3=0.f;
#pragma unroll 8
  for(int o=0;o<DH;o++){
    float qv = qsm[w*DH + o];
    float4 kk = *(const float4*)(kTs + o*NN + j0);
    s0=fmaf(qv,kk.x,s0); s1=fmaf(qv,kk.y,s1); s2=fmaf(qv,kk.z,s2); s3=fmaf(qv,kk.w,s3);
  }
  const float* __restrict__ e = ebg + (size_t)(i0+w)*768;
  float4 ex = *(const float4*)(e + j0);
  float4 ey = *(const float4*)(e + 256 + j0);
  float4 ez = *(const float4*)(e + 512 + j0);
  s0 = (s0 + qwe0*ex.x + qwe1*ey.x + qwe2*ez.x)*ATTN_SCALE;
  s1 = (s1 + qwe0*ex.y + qwe1*ey.y + qwe2*ez.y)*ATTN_SCALE;
  s2 = (s2 + qwe0*ex.z + qwe1*ey.z + qwe2*ez.z)*ATTN_SCALE;
  s3 = (s3 + qwe0*ex.w + qwe1*ey.w + qwe2*ez.w)*ATTN_SCALE;
  float mx = wred_max(fmaxf(fmaxf(s0,s1),fmaxf(s2,s3)));
  float p0=expf(s0-mx), p1=expf(s1-mx), p2=expf(s2-mx), p3=expf(s3-mx);
  float inv = 1.f / wred_sum(p0+p1+p2+p3);
  float a0=p0*inv, a1=p1*inv, a2=p2*inv, a3=p3*inv;
  *(float4*)(aW[w] + j0) = make_float4(a0,a1,a2,a3);
  float c0 = a0*ex.x + a1*ex.y + a2*ex.z + a3*ex.w;
  float c1 = a0*ey.x + a1*ey.y + a2*ey.z + a3*ey.w;
  float c2 = a0*ez.x + a1*ez.y + a2*ez.z + a3*ez.w;
  c0 = wred_sum(c0); c1 = wred_sum(c1); c2 = wred_sum(c2);
  __builtin_amdgcn_wave_barrier();   // order aW writes before same-wave aW reads
  // PV from LDS: lane l owns output dim qb+l; aW broadcast, vs 2-way-free
  const float* aww = aW[w];
  float acc0 = 0.f, acc1 = 0.f;
#pragma unroll 8
  for(int j=0;j<NN;j+=2){
    acc0 = fmaf(aww[j],   vs[j*64 + l],     acc0);
    acc1 = fmaf(aww[j+1], vs[(j+1)*64 + l], acc1);
  }
  float ov = acc0 + acc1
           + c0*We[0*INNER + qb + l]
           + c1*We[1*INNER + qb + l]
           + c2*We[2*INNER + qb + l];
  aog[(i0+w)*INNER + qb + l] = ov;
}

// ---- fused per-row layer tail: Wo+gate1+LN2+FFN+gate2 (+next QKV | energy) ----
__global__ __launch_bounds__(512) void k_layer(
    float* nodes, const float* __restrict__ aog,
    float* qg_n, float* kT_n, float* vg_n,
    const f16* __restrict__ Woh, const float* __restrict__ bo,
    const float* __restrict__ Wg1,
    const float* __restrict__ ln2_g, const float* __restrict__ ln2_b,
    const f16* __restrict__ W1h, const float* __restrict__ b1,
    const f16* __restrict__ W2h, const float* __restrict__ b2,
    const float* __restrict__ Wg2,
    const float* __restrict__ ln1_g_n, const float* __restrict__ ln1_b_n,
    const f16* __restrict__ Wqh_n, const float* __restrict__ bq_n,
    const float* __restrict__ Wkv_n, const float* __restrict__ bkv_n,
    const float* __restrict__ be_n,
    const float* __restrict__ out_w, const float* __restrict__ out_b,
    float* eout, int has_next)
{
  __shared__ __align__(16) float SC[6144];   // matvec partials
  __shared__ __align__(16) float qs[INNER];  // FFN hidden
  __shared__ __align__(16) float aos[INNER]; // attention output row
  __shared__ __align__(16) float xsm[DIM];
  const int t = threadIdx.x, i = blockIdx.x;
  const int w = t>>6, l = t&63;

  aos[t] = aog[i*INNER + t];
  float nd0 = nodes[i*DIM + l];        // per-wave redundant row state
  float nd1 = nodes[i*DIM + 64 + l];
  __syncthreads();                               // B1

  // ---- Wo (fp16) + gate1 + LN2 ----
  mvp512_128h(aos, Woh, SC, t);
  __syncthreads();                               // B2
  {
    float o0 = bo[l], o1 = bo[64+l];
#pragma unroll
    for(int fg=0; fg<32; fg++){ o0 += SC[fg*DIM + l]; o1 += SC[fg*DIM + 64 + l]; }
    gate_wave(o0, o1, nd0, nd1, Wg1, l);
    float x0, x1;
    ln_wave(nd0, nd1, ln2_g, ln2_b, l, x0, x1);
    xsm[l] = x0; xsm[64+l] = x1;
  }
  __syncthreads();                               // B3 (xsm ready; SC free)

  // ---- FFN (fp16) ----
  mvp128_512h(xsm, W1h, SC, t);
  __syncthreads();                               // B4
  {
    float a = b1[t];
#pragma unroll
    for(int fg=0; fg<8; fg++) a += SC[fg*INNER + t];
    qs[t] = 0.5f*a*(1.f + erff(a*0.70710678118654752440f));
  }
  __syncthreads();                               // B5 (hidden ready; SC free)
  mvp512_128h(qs, W2h, SC, t);
  __syncthreads();                               // B6
  {
    float y0 = b2[l], y1 = b2[64+l];
#pragma unroll
    for(int fg=0; fg<32; fg++){ y0 += SC[fg*DIM + l]; y1 += SC[fg*DIM + 64 + l]; }
    gate_wave(y0, y1, nd0, nd1, Wg2, l);
    if(w==0){ nodes[i*DIM + l] = nd0; nodes[i*DIM + 64 + l] = nd1; }
    if(has_next){
      float x0, x1;
      ln_wave(nd0, nd1, ln1_g_n, ln1_b_n, l, x0, x1);
      xsm[l] = x0; xsm[64+l] = x1;
    } else if(w==0){
      float ev = nd0*out_w[l] + nd1*out_w[64+l];
      ev = wred_sum(ev);
      if(l==0) eout[i] = ev + out_b[0];
    }
  }
  if(has_next){
    __syncthreads();                             // B7 (xsm ready; SC free)
    qkv_tail(xsm, i, Wqh_n, bq_n, Wkv_n, bkv_n, be_n,
             qg_n, kT_n, vg_n, SC, t);           // B8
  }
}

extern "C" void kernel_launch(void* const* d_in, const int* in_sizes, int n_in,
                              void* d_out, int out_size, void* d_ws, size_t ws_size,
                              hipStream_t stream){
  const float* coords   = (const float*)d_in[0];
  const int*   bonds    = (const int*  )d_in[1];
  const float* noise    = (const float*)d_in[2];
  const float* atom_emb = (const float*)d_in[3];
  const float* ln1_g = (const float*)d_in[4];
  const float* ln1_b = (const float*)d_in[5];
  const float* Wq    = (const float*)d_in[6];
  const float* bq    = (const float*)d_in[7];
  const float* Wkv   = (const float*)d_in[8];
  const float* bkv   = (const float*)d_in[9];
  const float* We    = (const float*)d_in[10];
  const float* be    = (const float*)d_in[11];
  const float* Wo    = (const float*)d_in[12];
  const float* bo    = (const float*)d_in[13];
  const float* Wg1   = (const float*)d_in[14];
  const float* ln2_g = (const float*)d_in[15];
  const float* ln2_b = (const float*)d_in[16];
  const float* W1    = (const float*)d_in[17];
  const float* b1    = (const float*)d_in[18];
  const float* W2    = (const float*)d_in[19];
  const float* b2    = (const float*)d_in[20];
  const float* Wg2   = (const float*)d_in[21];
  const float* out_w = (const float*)d_in[22];
  const float* out_b = (const float*)d_in[23];

  // workspace carve (bytes); total ~7.4 MB
  char* base = (char*)d_ws;
  float* nodes = (float*)(base);                    // 131072 B
  float* qb0   = (float*)(base + 131072);           // 524288 B
  float* qb1   = (float*)(base + 655360);
  float* aog   = (float*)(base + 1179648);
  float* ebg   = (float*)(base + 1703936);          // 786432 B
  float* kb0   = (float*)(base + 2490368);          // 524288 B
  float* kb1   = (float*)(base + 3014656);
  float* vb0   = (float*)(base + 3538944);
  float* vb1   = (float*)(base + 4063232);
  f16*   Wqh   = (f16*  )(base + 4587520);          // 786432 B
  f16*   Woh   = (f16*  )(base + 5373952);
  f16*   W1h   = (f16*  )(base + 6160384);
  f16*   W2h   = (f16*  )(base + 6946816);
  float* eout  = (float*)d_out;

  k_init<<<800, 512, 0, stream>>>(atom_emb, noise, nodes, ln1_g, ln1_b,
                                  Wq, bq, Wkv, bkv, be,
                                  qb0, kb0, vb0,
                                  bonds, coords, ebg,
                                  Wo, W1, W2, Wqh, Woh, W1h, W2h);
  for(int l=0; l<DEPTH; l++){
    int has_next = (l < DEPTH-1);
    int ln = has_next ? l+1 : l;    // keep pointers valid when unused
    float* qcur = (l&1)? qb1:qb0;  float* kcur = (l&1)? kb1:kb0;  float* vcur = (l&1)? vb1:vb0;
    float* qnxt = (l&1)? qb0:qb1;  float* knxt = (l&1)? kb0:kb1;  float* vnxt = (l&1)? vb0:vb1;
    const f16* Woh_l  = Woh + (size_t)l*INNER*DIM;
    const f16* W1h_l  = W1h + (size_t)l*DIM*4*DIM;
    const f16* W2h_l  = W2h + (size_t)l*4*DIM*DIM;
    const f16* Wqh_n  = Wqh + (size_t)ln*DIM*INNER;
    const float* Wkv_n = Wkv + (size_t)ln*DIM*2*INNER;
    k_attn<<<NN, 512, 0, stream>>>(
      qcur, kcur, vcur, ebg,
      We + (size_t)l*3*INNER, aog,
      Woh_l, W1h_l, W2h_l, Wqh_n, Wkv_n, has_next);
    k_layer<<<NN, 512, 0, stream>>>(
      nodes, aog,
      qnxt, knxt, vnxt,
      Woh_l, bo + (size_t)l*DIM, Wg1 + (size_t)l*3*DIM,
      ln2_g + (size_t)l*DIM, ln2_b + (size_t)l*DIM,
      W1h_l, b1 + (size_t)l*4*DIM,
      W2h_l, b2 + (size_t)l*DIM, Wg2 + (size_t)l*3*DIM,
      ln1_g + (size_t)ln*DIM, ln1_b + (size_t)ln*DIM,
      Wqh_n, bq + (size_t)ln*INNER,
      Wkv_n, bkv + (size_t)ln*2*INNER,
      be  + (size_t)ln*INNER,
      out_w, out_b, eout, has_next);
  }
}